// Round 5
// baseline (368.568 us; speedup 1.0000x reference)
//
#include <hip/hip_runtime.h>

typedef __bf16 bf16x8 __attribute__((ext_vector_type(8)));
typedef float floatx4 __attribute__((ext_vector_type(4)));

__device__ __forceinline__ unsigned short f2bf(float f) {
    union { float f; unsigned int u; } a;
    a.f = f;
    unsigned int u = a.u;
    unsigned int r = (u + 0x7FFFu + ((u >> 16) & 1u)) >> 16;  // RNE
    return (unsigned short)r;
}

__device__ __forceinline__ void async_copy16(const void* g, void* l) {
    __builtin_amdgcn_global_load_lds(
        (const __attribute__((address_space(1))) unsigned int*)g,
        (__attribute__((address_space(3))) unsigned int*)l,
        16, 0, 0);
}

__device__ __forceinline__ float sigmoidf_fast(float x) {
    return 1.f / (1.f + __expf(-x));
}
__device__ __forceinline__ float tanhf_fast(float x) {
    return 1.f - 2.f / (__expf(2.f * x) + 1.f);
}

// Prep: [x|h] -> Abf [8192,2048] bf16 (identity rows) and [Wx|Wh] -> Wbf
// [4096,2048] bf16 with FINE gate interleave: output row n' decomposes as
//   tile = n'>>7, c = n'&127, gate = (c>>4)&3, h = tile*32 + (c>>6)*16 + (c&15)
//   source row = gate*1024 + h
// so a wave's 4 j-fragments hold the 4 gates of one h value (no LDS exchange).
__global__ void prep_cat(const float* __restrict__ x, const float* __restrict__ h,
                         const float* __restrict__ Wx, const float* __restrict__ Wh,
                         unsigned short* __restrict__ Abf, unsigned short* __restrict__ Wbf) {
    int T = blockIdx.x * 256 + threadIdx.x;
    const float* a;
    const float* b;
    unsigned short* o;
    size_t e;
    size_t srow;
    if (T < 4194304) {
        e = (size_t)T * 4;
        a = x; b = h; o = Abf;
        srow = e >> 11;
    } else {
        e = (size_t)(T - 4194304) * 4;
        a = Wx; b = Wh; o = Wbf;
        int m = (int)(e >> 11);                 // permuted (output) row
        int tile = m >> 7, c = m & 127;
        int gate = (c >> 4) & 3;
        int hv = tile * 32 + (c >> 6) * 16 + (c & 15);
        srow = (size_t)(gate * 1024 + hv);
    }
    int k = (int)(e & 2047);
    const float* src = (k < 1024) ? (a + srow * 1024 + k)
                                  : (b + srow * 1024 + (k - 1024));
    float4 v = *(const float4*)src;
    ushort4 u;
    u.x = f2bf(v.x); u.y = f2bf(v.y); u.z = f2bf(v.z); u.w = f2bf(v.w);
    *(ushort4*)(o + e) = u;
}

__device__ __forceinline__ bf16x8 ldfrag(const char* base, int row, int chunk) {
    int c = chunk ^ ((row >> 1) & 3);     // undo XOR staging swizzle
    return *(const bf16x8*)(base + row * 64 + c * 16);
}

// Fused GEMM + LSTM. Round-1 K-loop (128x128 tile, BK=32, 4 waves of 4x4
// mfma_f32_16x16x32_bf16). W fine-gate-interleaved: acc[i][j] is gate j of
// h = blockIdx.x*32 + wn*16 + l15, rows tileM + wm*64 + i*16 + quad*4 + v.
// acc initialized to bias; epilogue is pure-register LSTM math + stores.
__global__ __launch_bounds__(256) void gemm_lstm(
    const unsigned short* __restrict__ A,     // [8192,2048] bf16
    const unsigned short* __restrict__ W,     // [4096,2048] bf16, gate-interleaved rows
    const float* __restrict__ bx, const float* __restrict__ bh,
    const float* __restrict__ c1,             // [8192,1024] f32
    float* __restrict__ out) {                // h_new [8192,1024] then c [8192,1024]
    __shared__ __align__(16) char smem[16384];
    char* As = smem;            // 128 rows x 64 B (32 bf16), XOR chunk swizzle
    char* Bs = smem + 8192;

    const int t = threadIdx.x;
    const int lane = t & 63;
    const int wave = t >> 6;
    const int tileN = blockIdx.x * 128;
    const int tileM = blockIdx.y * 128;
    const int wm = wave & 1;
    const int wn = wave >> 1;
    const int l15 = lane & 15;
    const int quad = lane >> 4;

    // this thread's h column and bias-initialized accumulators
    const int hglob = blockIdx.x * 32 + wn * 16 + l15;
    floatx4 acc[4][4];
#pragma unroll
    for (int j = 0; j < 4; ++j) {
        float b = bx[j * 1024 + hglob] + bh[j * 1024 + hglob];
        floatx4 bv = {b, b, b, b};
#pragma unroll
        for (int i = 0; i < 4; ++i) acc[i][j] = bv;
    }

    const int lr = wave * 16 + (lane >> 2);
    const int lq = lane & 3;

    for (int kt = 0; kt < 2048; kt += 32) {
#pragma unroll
        for (int j = 0; j < 2; ++j) {
            int r = j * 64 + lr;
            int qg = lq ^ ((r >> 1) & 3);
            const unsigned short* ga = A + (size_t)(tileM + r) * 2048 + kt + qg * 8;
            async_copy16(ga, As + j * 4096 + wave * 1024);
            const unsigned short* gb = W + (size_t)(tileN + r) * 2048 + kt + qg * 8;
            async_copy16(gb, Bs + j * 4096 + wave * 1024);
        }
        __syncthreads();

        bf16x8 af[4], bf[4];
#pragma unroll
        for (int i = 0; i < 4; ++i)
            af[i] = ldfrag(As, wm * 64 + i * 16 + l15, quad);
#pragma unroll
        for (int j = 0; j < 4; ++j)
            bf[j] = ldfrag(Bs, wn * 64 + j * 16 + l15, quad);
#pragma unroll
        for (int i = 0; i < 4; ++i)
#pragma unroll
            for (int j = 0; j < 4; ++j)
                acc[i][j] = __builtin_amdgcn_mfma_f32_16x16x32_bf16(af[i], bf[j], acc[i][j], 0, 0, 0);
        __syncthreads();
    }

    // ---- epilogue: all 4 gates of h=hglob are in registers; 16 rows/thread ----
#pragma unroll
    for (int i = 0; i < 4; ++i) {
        int rowbase = tileM + wm * 64 + i * 16 + quad * 4;
        // prefetch the 4 c1 values for this i
        float c1v[4];
        size_t goff0 = (size_t)rowbase * 1024 + hglob;
#pragma unroll
        for (int v = 0; v < 4; ++v) c1v[v] = c1[goff0 + (size_t)v * 1024];
#pragma unroll
        for (int v = 0; v < 4; ++v) {
            float gi = acc[i][0][v];
            float gf = acc[i][1][v];
            float go = acc[i][2][v];
            float gc = acc[i][3][v];
            float ii = sigmoidf_fast(gi);
            float ff = sigmoidf_fast(gf);
            float oo = sigmoidf_fast(go);
            float cb = tanhf_fast(gc);
            float cc = sigmoidf_fast(ff * c1v[v] + ii * cb);  // reference quirk: sigmoid on cell
            float hn = tanhf_fast(cc) * oo;
            size_t goff = goff0 + (size_t)v * 1024;
            out[goff] = hn;
            out[8388608 + goff] = cc;
        }
    }
}

extern "C" void kernel_launch(void* const* d_in, const int* in_sizes, int n_in,
                              void* d_out, int out_size, void* d_ws, size_t ws_size,
                              hipStream_t stream) {
    const float* x  = (const float*)d_in[0];
    const float* h  = (const float*)d_in[1];
    const float* c1 = (const float*)d_in[2];
    const float* Wx = (const float*)d_in[3];
    const float* bx = (const float*)d_in[4];
    const float* Wh = (const float*)d_in[5];
    const float* bh = (const float*)d_in[6];
    float* out = (float*)d_out;

    char* ws = (char*)d_ws;
    unsigned short* Abf = (unsigned short*)(ws);                // 33,554,432 B
    unsigned short* Wbf = (unsigned short*)(ws + 33554432);     // 16,777,216 B

    prep_cat<<<24576, 256, 0, stream>>>(x, h, Wx, Wh, Abf, Wbf);
    dim3 grid(32, 64);   // x: N-tiles (gate-interleaved cols), y: M-tiles
    gemm_lstm<<<grid, 256, 0, stream>>>(Abf, Wbf, bx, bh, c1, out);
}